// Round 1
// baseline (816.604 us; speedup 1.0000x reference)
//
#include <hip/hip_runtime.h>
#include <stdint.h>

#define DMODEL 1024
#define NHEAD 16
#define DH 64
#define BB 4
#define SS 2048
#define MROWS (BB * SS)   // 8192

typedef __bf16 bfx8 __attribute__((ext_vector_type(8)));
typedef float f32x4 __attribute__((ext_vector_type(4)));
typedef float fvec4 __attribute__((ext_vector_type(4)));
typedef unsigned short u16x8 __attribute__((ext_vector_type(8)));
typedef unsigned short u16x4 __attribute__((ext_vector_type(4)));

__device__ __forceinline__ unsigned short f2bf(float f) {
    union { float f; unsigned int u; } v; v.f = f;
    unsigned int r = v.u + 0x7FFFu + ((v.u >> 16) & 1u);
    return (unsigned short)(r >> 16);
}

// ---------------------------------------------------------------------------
// GEMM: out[M][N] = A[M][K] @ B[K][N] + bias[N]
// A is fp32 or bf16 (ushort); B/bias fp32; out bf16 (ushort) or fp32.
// 128x128 tile, BK=32, 256 threads = 4 waves (2x2), 16x16x32 bf16 MFMA.
// ---------------------------------------------------------------------------
template<bool A_BF16, bool OUT_BF16>
__global__ __launch_bounds__(256, 2)
void gemm_bias_kernel(const void* __restrict__ Av, const float* __restrict__ Bm,
                      const float* __restrict__ bias, void* __restrict__ Ov,
                      int M, int N, int K)
{
    __shared__ unsigned short sA[128][40];   // [m][k], pad 32->40 (80B rows)
    __shared__ unsigned short sB[128][40];   // transposed: [n][k]
    const int tid  = threadIdx.x;
    const int lane = tid & 63;
    const int wave = tid >> 6;
    const int wm = (wave >> 1) * 64, wn = (wave & 1) * 64;
    const int m0 = blockIdx.x * 128, n0 = blockIdx.y * 128;
    const int lr = lane & 15;   // fragment row/col
    const int lg = lane >> 4;   // k-group

    f32x4 acc[4][4] = {};

    for (int kk0 = 0; kk0 < K; kk0 += 32) {
        __syncthreads();
        // ---- stage A tile (128x32) -> bf16 LDS
        if (A_BF16) {
            const unsigned short* A = (const unsigned short*)Av;
            #pragma unroll
            for (int i = 0; i < 4; ++i) {
                int idx = tid + i * 256;            // 0..1023
                int ar = idx >> 3, ac4 = idx & 7;
                u16x4 vv = *reinterpret_cast<const u16x4*>(
                    &A[(size_t)(m0 + ar) * K + kk0 + ac4 * 4]);
                *reinterpret_cast<u16x4*>(&sA[ar][ac4 * 4]) = vv;
            }
        } else {
            const float* A = (const float*)Av;
            #pragma unroll
            for (int i = 0; i < 4; ++i) {
                int idx = tid + i * 256;
                int ar = idx >> 3, ac4 = idx & 7;
                fvec4 vv = *reinterpret_cast<const fvec4*>(
                    &A[(size_t)(m0 + ar) * K + kk0 + ac4 * 4]);
                u16x4 bb;
                #pragma unroll
                for (int j = 0; j < 4; ++j) bb[j] = f2bf(vv[j]);
                *reinterpret_cast<u16x4*>(&sA[ar][ac4 * 4]) = bb;
            }
        }
        // ---- stage B tile (32x128), transposed into sB[n][k]
        #pragma unroll
        for (int i = 0; i < 4; ++i) {
            int idx = tid + i * 256;
            int br = idx >> 5, bc4 = idx & 31;      // k-row 0..31, colgrp 0..31
            fvec4 vv = *reinterpret_cast<const fvec4*>(
                &Bm[(size_t)(kk0 + br) * N + n0 + bc4 * 4]);
            #pragma unroll
            for (int j = 0; j < 4; ++j) sB[bc4 * 4 + j][br] = f2bf(vv[j]);
        }
        __syncthreads();

        bfx8 af[4], bfr[4];
        #pragma unroll
        for (int m = 0; m < 4; ++m)
            af[m] = *reinterpret_cast<const bfx8*>(&sA[wm + m * 16 + lr][lg * 8]);
        #pragma unroll
        for (int n = 0; n < 4; ++n)
            bfr[n] = *reinterpret_cast<const bfx8*>(&sB[wn + n * 16 + lr][lg * 8]);
        #pragma unroll
        for (int m = 0; m < 4; ++m)
            #pragma unroll
            for (int n = 0; n < 4; ++n)
                acc[m][n] = __builtin_amdgcn_mfma_f32_16x16x32_bf16(
                    af[m], bfr[n], acc[m][n], 0, 0, 0);
    }

    // ---- epilogue: + bias, store
    #pragma unroll
    for (int n = 0; n < 4; ++n) {
        int col = n0 + wn + n * 16 + lr;
        float bv = bias[col];
        #pragma unroll
        for (int m = 0; m < 4; ++m) {
            int rowb = m0 + wm + m * 16 + lg * 4;
            #pragma unroll
            for (int r = 0; r < 4; ++r) {
                float val = acc[m][n][r] + bv;
                if (OUT_BF16)
                    ((unsigned short*)Ov)[(size_t)(rowb + r) * N + col] = f2bf(val);
                else
                    ((float*)Ov)[(size_t)(rowb + r) * N + col] = val;
            }
        }
    }
}

// ---------------------------------------------------------------------------
// Flash-style causal attention over bf16 Q/K/V laid out [B*S][H*DH].
// Grid: x = S/64 q-tiles, y = B*H. Block 256 = 4 waves x 16 q-rows.
// scores scaled by 1/sqrt(MAX_LEN) = 1/sqrt(2048) per the reference.
// ---------------------------------------------------------------------------
__global__ __launch_bounds__(256, 2)
void attn_kernel(const unsigned short* __restrict__ Q,
                 const unsigned short* __restrict__ K,
                 const unsigned short* __restrict__ V,
                 unsigned short* __restrict__ C)
{
    __shared__ unsigned short sK[64][72];        // [k][d], pad 64->72
    __shared__ unsigned short sVt[64][72];       // [d][k]
    __shared__ unsigned short sP[4][16][72];     // per-wave P tile [q][k]

    const int tid  = threadIdx.x;
    const int lane = tid & 63;
    const int wave = tid >> 6;
    const int lr = lane & 15, lg = lane >> 4;
    const int qt = blockIdx.x;
    const int bh = blockIdx.y;
    const int b = bh >> 4, h = bh & 15;
    const int q0 = qt * 64;
    const size_t rowbase = (size_t)b * SS;
    const int hcol = h * DH;
    const float scale = 0.02209708691207961f;    // 1/sqrt(2048)

    // Q fragments for this wave's 16 rows (d = 0..63 in two 32-chunks)
    bfx8 aq0, aq1;
    {
        int qr = q0 + wave * 16 + lr;
        const unsigned short* p = &Q[(rowbase + qr) * DMODEL + hcol + lg * 8];
        aq0 = *reinterpret_cast<const bfx8*>(p);
        aq1 = *reinterpret_cast<const bfx8*>(p + 32);
    }

    float m_run[4], l_run[4];
    f32x4 acc_o[4];
    #pragma unroll
    for (int r = 0; r < 4; ++r) { m_run[r] = -3.0e38f; l_run[r] = 0.f; }
    #pragma unroll
    for (int d = 0; d < 4; ++d) acc_o[d] = f32x4{0.f, 0.f, 0.f, 0.f};

    for (int t = 0; t <= qt; ++t) {
        const int k0 = t * 64;
        __syncthreads();
        // ---- stage K tile and transposed V tile
        #pragma unroll
        for (int i = 0; i < 2; ++i) {
            int idx = tid + i * 256;                 // 0..511
            int kr = idx >> 3, kc8 = idx & 7;
            u16x8 kv = *reinterpret_cast<const u16x8*>(
                &K[(rowbase + k0 + kr) * DMODEL + hcol + kc8 * 8]);
            *reinterpret_cast<u16x8*>(&sK[kr][kc8 * 8]) = kv;
            u16x8 vv = *reinterpret_cast<const u16x8*>(
                &V[(rowbase + k0 + kr) * DMODEL + hcol + kc8 * 8]);
            #pragma unroll
            for (int j = 0; j < 8; ++j) sVt[kc8 * 8 + j][kr] = vv[j];
        }
        __syncthreads();

        // ---- scores: S = Q @ K^T  (16 q-rows x 64 k-cols per wave)
        f32x4 sc[4];
        #pragma unroll
        for (int nf = 0; nf < 4; ++nf) {
            bfx8 bk0 = *reinterpret_cast<const bfx8*>(&sK[nf * 16 + lr][lg * 8]);
            bfx8 bk1 = *reinterpret_cast<const bfx8*>(&sK[nf * 16 + lr][32 + lg * 8]);
            f32x4 s = {0.f, 0.f, 0.f, 0.f};
            s = __builtin_amdgcn_mfma_f32_16x16x32_bf16(aq0, bk0, s, 0, 0, 0);
            s = __builtin_amdgcn_mfma_f32_16x16x32_bf16(aq1, bk1, s, 0, 0, 0);
            sc[nf] = s;
        }
        // ---- scale + causal mask
        const int qg_base = q0 + wave * 16 + lg * 4;
        #pragma unroll
        for (int nf = 0; nf < 4; ++nf) {
            int kg = k0 + nf * 16 + lr;
            #pragma unroll
            for (int r = 0; r < 4; ++r) {
                float sv = sc[nf][r] * scale;
                sc[nf][r] = (kg <= qg_base + r) ? sv : -3.0e38f;
            }
        }
        // ---- online softmax (row = across 16 lanes of the lane-group + 4 nf)
        float mnew[4], fscl[4];
        #pragma unroll
        for (int r = 0; r < 4; ++r) {
            float mx = fmaxf(fmaxf(sc[0][r], sc[1][r]), fmaxf(sc[2][r], sc[3][r]));
            #pragma unroll
            for (int o = 1; o < 16; o <<= 1) mx = fmaxf(mx, __shfl_xor(mx, o, 64));
            mnew[r] = fmaxf(m_run[r], mx);
            fscl[r] = __expf(m_run[r] - mnew[r]);
            m_run[r] = mnew[r];
        }
        #pragma unroll
        for (int r = 0; r < 4; ++r) {
            float ps = 0.f;
            #pragma unroll
            for (int nf = 0; nf < 4; ++nf) {
                float p = __expf(sc[nf][r] - mnew[r]);
                sc[nf][r] = p;
                ps += p;
            }
            #pragma unroll
            for (int o = 1; o < 16; o <<= 1) ps += __shfl_xor(ps, o, 64);
            l_run[r] = l_run[r] * fscl[r] + ps;
        }
        // ---- write P (bf16) to per-wave LDS tile
        #pragma unroll
        for (int nf = 0; nf < 4; ++nf)
            #pragma unroll
            for (int r = 0; r < 4; ++r)
                sP[wave][lg * 4 + r][nf * 16 + lr] = f2bf(sc[nf][r]);
        asm volatile("s_waitcnt lgkmcnt(0)" ::: "memory");
        // ---- rescale O then accumulate P @ V
        #pragma unroll
        for (int d = 0; d < 4; ++d)
            #pragma unroll
            for (int r = 0; r < 4; ++r) acc_o[d][r] *= fscl[r];

        bfx8 ap0 = *reinterpret_cast<const bfx8*>(&sP[wave][lr][lg * 8]);
        bfx8 ap1 = *reinterpret_cast<const bfx8*>(&sP[wave][lr][32 + lg * 8]);
        #pragma unroll
        for (int d = 0; d < 4; ++d) {
            bfx8 bv0 = *reinterpret_cast<const bfx8*>(&sVt[d * 16 + lr][lg * 8]);
            bfx8 bv1 = *reinterpret_cast<const bfx8*>(&sVt[d * 16 + lr][32 + lg * 8]);
            acc_o[d] = __builtin_amdgcn_mfma_f32_16x16x32_bf16(ap0, bv0, acc_o[d], 0, 0, 0);
            acc_o[d] = __builtin_amdgcn_mfma_f32_16x16x32_bf16(ap1, bv1, acc_o[d], 0, 0, 0);
        }
    }

    // ---- epilogue: O / l, store bf16 into C layout [B*S][H*DH]
    const int qrb = q0 + wave * 16 + lg * 4;
    #pragma unroll
    for (int d = 0; d < 4; ++d) {
        int col = hcol + d * 16 + lr;
        #pragma unroll
        for (int r = 0; r < 4; ++r) {
            float val = acc_o[d][r] / l_run[r];
            C[(rowbase + qrb + r) * DMODEL + col] = f2bf(val);
        }
    }
}

// ---------------------------------------------------------------------------
extern "C" void kernel_launch(void* const* d_in, const int* in_sizes, int n_in,
                              void* d_out, int out_size, void* d_ws, size_t ws_size,
                              hipStream_t stream)
{
    const float* q  = (const float*)d_in[0];
    const float* k  = (const float*)d_in[1];
    const float* v  = (const float*)d_in[2];
    const float* Wq = (const float*)d_in[3];
    const float* bq = (const float*)d_in[4];
    const float* Wk = (const float*)d_in[5];
    const float* bk = (const float*)d_in[6];
    const float* Wv = (const float*)d_in[7];
    const float* bv = (const float*)d_in[8];
    const float* Wf = (const float*)d_in[9];
    const float* bf = (const float*)d_in[10];
    float* out = (float*)d_out;

    unsigned short* ws = (unsigned short*)d_ws;
    const size_t SZ = (size_t)MROWS * DMODEL;  // 8388608 elements
    unsigned short* Qb = ws;
    unsigned short* Kb = ws + SZ;
    unsigned short* Vb = ws + 2 * SZ;
    unsigned short* Cb = ws + 3 * SZ;

    dim3 gblk(MROWS / 128, DMODEL / 128);      // 64 x 8
    gemm_bias_kernel<false, true><<<gblk, 256, 0, stream>>>(q, Wq, bq, Qb, MROWS, DMODEL, DMODEL);
    gemm_bias_kernel<false, true><<<gblk, 256, 0, stream>>>(k, Wk, bk, Kb, MROWS, DMODEL, DMODEL);
    gemm_bias_kernel<false, true><<<gblk, 256, 0, stream>>>(v, Wv, bv, Vb, MROWS, DMODEL, DMODEL);

    attn_kernel<<<dim3(SS / 64, BB * NHEAD), 256, 0, stream>>>(Qb, Kb, Vb, Cb);

    gemm_bias_kernel<true, false><<<gblk, 256, 0, stream>>>(Cb, Wf, bf, out, MROWS, DMODEL, DMODEL);
}

// Round 2
// 355.394 us; speedup vs baseline: 2.2977x; 2.2977x over previous
//
#include <hip/hip_runtime.h>
#include <stdint.h>

#define DMODEL 1024
#define NHEAD 16
#define DH 64
#define BB 4
#define SS 2048
#define MROWS (BB * SS)   // 8192

typedef __bf16 bfx8 __attribute__((ext_vector_type(8)));
typedef float f32x4 __attribute__((ext_vector_type(4)));
typedef float fvec4 __attribute__((ext_vector_type(4)));
typedef unsigned short u16x8 __attribute__((ext_vector_type(8)));
typedef unsigned short u16x4 __attribute__((ext_vector_type(4)));

__device__ __forceinline__ unsigned short f2bf(float f) {
    union { float f; unsigned int u; } v; v.f = f;
    unsigned int r = v.u + 0x7FFFu + ((v.u >> 16) & 1u);
    return (unsigned short)(r >> 16);
}

// async global->LDS, 16B per lane. LDS dest must be linear: wave base + lane*16.
typedef __attribute__((address_space(1))) const void gas_t;
typedef __attribute__((address_space(3))) void las_t;
__device__ __forceinline__ void gload_lds16(const void* g, void* l) {
    __builtin_amdgcn_global_load_lds((gas_t*)g, (las_t*)l, 16, 0, 0);
}

// ---------------------------------------------------------------------------
// Transpose + convert: Wt[n][k] (bf16) = W[k][n] (fp32).  64x64 tiles.
// ---------------------------------------------------------------------------
__global__ void transpose_cvt_kernel(const float* __restrict__ W,
                                     unsigned short* __restrict__ Wt,
                                     int rows, int cols)
{
    __shared__ unsigned short t[64][76];
    const int tid = threadIdx.x;
    const int r0 = blockIdx.y * 64, c0 = blockIdx.x * 64;
    #pragma unroll
    for (int i = 0; i < 4; ++i) {
        int idx = tid + i * 256;                 // 0..1023
        int r = idx >> 4, c4 = idx & 15;
        fvec4 v = *reinterpret_cast<const fvec4*>(&W[(size_t)(r0 + r) * cols + c0 + c4 * 4]);
        #pragma unroll
        for (int j = 0; j < 4; ++j) t[c4 * 4 + j][r] = f2bf(v[j]);
    }
    __syncthreads();
    #pragma unroll
    for (int i = 0; i < 2; ++i) {
        int idx = tid + i * 256;                 // 0..511
        int r = idx >> 3, c8 = idx & 7;
        u16x8 v = *reinterpret_cast<const u16x8*>(&t[r][c8 * 8]);
        *reinterpret_cast<u16x8*>(&Wt[(size_t)(c0 + r) * rows + r0 + c8 * 8]) = v;
    }
}

// ---------------------------------------------------------------------------
// Per-head V transpose: Vt[bh][d][s] = Vb[b*S+s][h*64+d]  (bf16 -> bf16)
// ---------------------------------------------------------------------------
__global__ void transpose_v_kernel(const unsigned short* __restrict__ Vb,
                                   unsigned short* __restrict__ Vt)
{
    __shared__ unsigned short t[64][76];
    const int tid = threadIdx.x;
    const int s0 = blockIdx.x * 64, bh = blockIdx.y;
    const int b = bh >> 4, h = bh & 15;
    #pragma unroll
    for (int i = 0; i < 2; ++i) {
        int idx = tid + i * 256;
        int sr = idx >> 3, c8 = idx & 7;
        u16x8 v = *reinterpret_cast<const u16x8*>(
            &Vb[((size_t)b * SS + s0 + sr) * DMODEL + h * DH + c8 * 8]);
        #pragma unroll
        for (int j = 0; j < 8; ++j) t[c8 * 8 + j][sr] = v[j];
    }
    __syncthreads();
    #pragma unroll
    for (int i = 0; i < 2; ++i) {
        int idx = tid + i * 256;
        int dr = idx >> 3, s8 = idx & 7;
        u16x8 v = *reinterpret_cast<const u16x8*>(&t[dr][s8 * 8]);
        *reinterpret_cast<u16x8*>(&Vt[((size_t)bh * DH + dr) * SS + s0 + s8 * 8]) = v;
    }
}

// ---------------------------------------------------------------------------
// GEMM: out[M][N] = A[M][K] @ Bt[N][K]^T + bias[N]
// A fp32 (reg-staged w/ convert) or bf16 (global_load_lds); Bt bf16 via
// global_load_lds. 128x128 tile, BK=64, 256 thr = 4 waves, 32 MFMA/k-step.
// ---------------------------------------------------------------------------
template<bool A_BF16, bool OUT_BF16>
__global__ __launch_bounds__(256, 2)
void gemm_kernel(const void* __restrict__ Av, const unsigned short* __restrict__ Bt,
                 const float* __restrict__ bias, void* __restrict__ Ov,
                 int M, int N, int K)
{
    __shared__ unsigned short sA[128 * 64];
    __shared__ unsigned short sB[128 * 64];
    const int tid  = threadIdx.x;
    const int lane = tid & 63;
    const int wave = tid >> 6;
    const int wm = (wave >> 1) * 64, wn = (wave & 1) * 64;
    const int m0 = blockIdx.x * 128, n0 = blockIdx.y * 128;
    const int lr = lane & 15;
    const int lg = lane >> 4;

    f32x4 acc[4][4] = {};

    for (int kk0 = 0; kk0 < K; kk0 += 64) {
        __syncthreads();
        // ---- stage A (128x64 bf16)
        if (A_BF16) {
            const unsigned short* A = (const unsigned short*)Av;
            #pragma unroll
            for (int i = 0; i < 4; ++i) {
                int c = tid + i * 256;               // 16B chunk id 0..1023
                int row = c >> 3, col8 = c & 7;
                gload_lds16(&A[(size_t)(m0 + row) * K + kk0 + col8 * 8], &sA[c * 8]);
            }
        } else {
            const float* A = (const float*)Av;
            #pragma unroll
            for (int i = 0; i < 8; ++i) {
                int idx = tid + i * 256;             // 0..2047
                int ar = idx >> 4, ac4 = idx & 15;
                fvec4 v = *reinterpret_cast<const fvec4*>(
                    &A[(size_t)(m0 + ar) * K + kk0 + ac4 * 4]);
                u16x4 bb;
                #pragma unroll
                for (int j = 0; j < 4; ++j) bb[j] = f2bf(v[j]);
                *reinterpret_cast<u16x4*>(&sA[ar * 64 + ac4 * 4]) = bb;
            }
        }
        // ---- stage B (128x64 bf16) from pre-transposed weights
        #pragma unroll
        for (int i = 0; i < 4; ++i) {
            int c = tid + i * 256;
            int row = c >> 3, col8 = c & 7;
            gload_lds16(&Bt[(size_t)(n0 + row) * K + kk0 + col8 * 8], &sB[c * 8]);
        }
        __syncthreads();

        bfx8 af[4][2], bfr[4][2];
        #pragma unroll
        for (int m = 0; m < 4; ++m)
            #pragma unroll
            for (int kk = 0; kk < 2; ++kk)
                af[m][kk] = *reinterpret_cast<const bfx8*>(
                    &sA[(wm + m * 16 + lr) * 64 + kk * 32 + lg * 8]);
        #pragma unroll
        for (int n = 0; n < 4; ++n)
            #pragma unroll
            for (int kk = 0; kk < 2; ++kk)
                bfr[n][kk] = *reinterpret_cast<const bfx8*>(
                    &sB[(wn + n * 16 + lr) * 64 + kk * 32 + lg * 8]);
        #pragma unroll
        for (int kk = 0; kk < 2; ++kk)
            #pragma unroll
            for (int m = 0; m < 4; ++m)
                #pragma unroll
                for (int n = 0; n < 4; ++n)
                    acc[m][n] = __builtin_amdgcn_mfma_f32_16x16x32_bf16(
                        af[m][kk], bfr[n][kk], acc[m][n], 0, 0, 0);
    }

    #pragma unroll
    for (int n = 0; n < 4; ++n) {
        int col = n0 + wn + n * 16 + lr;
        float bv = bias[col];
        #pragma unroll
        for (int m = 0; m < 4; ++m) {
            int rowb = m0 + wm + m * 16 + lg * 4;
            #pragma unroll
            for (int r = 0; r < 4; ++r) {
                float val = acc[m][n][r] + bv;
                if (OUT_BF16)
                    ((unsigned short*)Ov)[(size_t)(rowb + r) * N + col] = f2bf(val);
                else
                    ((float*)Ov)[(size_t)(rowb + r) * N + col] = val;
            }
        }
    }
}

// ---------------------------------------------------------------------------
// Flash-style causal attention. Q,K: [B*S][H*DH] bf16; Vt: [B*H][DH][S] bf16.
// Grid: x = B*H (64), y = q-tiles (32, heavy-first). 256 thr = 4 waves x 16 q.
// Softmax in exp2 domain (scale folded with log2e).
// ---------------------------------------------------------------------------
__global__ __launch_bounds__(256, 2)
void attn_kernel(const unsigned short* __restrict__ Q,
                 const unsigned short* __restrict__ K,
                 const unsigned short* __restrict__ Vt,
                 unsigned short* __restrict__ C)
{
    __shared__ unsigned short sK[64][72];        // [k][d]
    __shared__ unsigned short sVt[64][72];       // [d][k]
    __shared__ unsigned short sP[4][16][72];     // per-wave P [q][k]

    const int tid  = threadIdx.x;
    const int lane = tid & 63;
    const int wave = tid >> 6;
    const int lr = lane & 15, lg = lane >> 4;
    const int bh = blockIdx.x;
    const int qt = (int)(gridDim.y - 1) - (int)blockIdx.y;   // heavy tiles first
    const int b = bh >> 4, h = bh & 15;
    const int q0 = qt * 64;
    const size_t rowbase = (size_t)b * SS;
    const int hcol = h * DH;
    const float scl2 = 0.02209708691207961f * 1.44269504088896341f; // /sqrt(2048) * log2(e)

    bfx8 aq0, aq1;
    {
        int qr = q0 + wave * 16 + lr;
        const unsigned short* p = &Q[(rowbase + qr) * DMODEL + hcol + lg * 8];
        aq0 = *reinterpret_cast<const bfx8*>(p);
        aq1 = *reinterpret_cast<const bfx8*>(p + 32);
    }

    float m_run[4], l_run[4];
    f32x4 acc_o[4];
    #pragma unroll
    for (int r = 0; r < 4; ++r) { m_run[r] = -3.0e38f; l_run[r] = 0.f; }
    #pragma unroll
    for (int d = 0; d < 4; ++d) acc_o[d] = f32x4{0.f, 0.f, 0.f, 0.f};

    for (int t = 0; t <= qt; ++t) {
        const int k0 = t * 64;
        __syncthreads();
        #pragma unroll
        for (int i = 0; i < 2; ++i) {
            int idx = tid + i * 256;
            int kr = idx >> 3, c8 = idx & 7;
            *reinterpret_cast<u16x8*>(&sK[kr][c8 * 8]) =
                *reinterpret_cast<const u16x8*>(
                    &K[(rowbase + k0 + kr) * DMODEL + hcol + c8 * 8]);
            *reinterpret_cast<u16x8*>(&sVt[kr][c8 * 8]) =
                *reinterpret_cast<const u16x8*>(
                    &Vt[((size_t)bh * DH + kr) * SS + k0 + c8 * 8]);
        }
        __syncthreads();

        // ---- S = Q @ K^T (16 q x 64 k per wave)
        f32x4 sc[4];
        #pragma unroll
        for (int nf = 0; nf < 4; ++nf) {
            bfx8 bk0 = *reinterpret_cast<const bfx8*>(&sK[nf * 16 + lr][lg * 8]);
            bfx8 bk1 = *reinterpret_cast<const bfx8*>(&sK[nf * 16 + lr][32 + lg * 8]);
            f32x4 s = {0.f, 0.f, 0.f, 0.f};
            s = __builtin_amdgcn_mfma_f32_16x16x32_bf16(aq0, bk0, s, 0, 0, 0);
            s = __builtin_amdgcn_mfma_f32_16x16x32_bf16(aq1, bk1, s, 0, 0, 0);
            sc[nf] = s;
        }
        // ---- scale (log2 domain) + causal mask
        const int qg_base = q0 + wave * 16 + lg * 4;
        #pragma unroll
        for (int nf = 0; nf < 4; ++nf) {
            int kg = k0 + nf * 16 + lr;
            #pragma unroll
            for (int r = 0; r < 4; ++r) {
                float sv = sc[nf][r] * scl2;
                sc[nf][r] = (kg <= qg_base + r) ? sv : -3.0e38f;
            }
        }
        // ---- online softmax (exp2 domain)
        float mnew[4], fscl[4];
        #pragma unroll
        for (int r = 0; r < 4; ++r) {
            float mx = fmaxf(fmaxf(sc[0][r], sc[1][r]), fmaxf(sc[2][r], sc[3][r]));
            #pragma unroll
            for (int o = 1; o < 16; o <<= 1) mx = fmaxf(mx, __shfl_xor(mx, o, 64));
            mnew[r] = fmaxf(m_run[r], mx);
            fscl[r] = __builtin_exp2f(m_run[r] - mnew[r]);
            m_run[r] = mnew[r];
        }
        #pragma unroll
        for (int r = 0; r < 4; ++r) {
            float ps = 0.f;
            #pragma unroll
            for (int nf = 0; nf < 4; ++nf) {
                float p = __builtin_exp2f(sc[nf][r] - mnew[r]);
                sc[nf][r] = p;
                ps += p;
            }
            #pragma unroll
            for (int o = 1; o < 16; o <<= 1) ps += __shfl_xor(ps, o, 64);
            l_run[r] = l_run[r] * fscl[r] + ps;
        }
        // ---- P -> LDS (bf16), per-wave tile
        #pragma unroll
        for (int nf = 0; nf < 4; ++nf)
            #pragma unroll
            for (int r = 0; r < 4; ++r)
                sP[wave][lg * 4 + r][nf * 16 + lr] = f2bf(sc[nf][r]);
        asm volatile("s_waitcnt lgkmcnt(0)" ::: "memory");
        // ---- rescale O, accumulate P @ V
        #pragma unroll
        for (int d = 0; d < 4; ++d)
            #pragma unroll
            for (int r = 0; r < 4; ++r) acc_o[d][r] *= fscl[r];

        bfx8 ap0 = *reinterpret_cast<const bfx8*>(&sP[wave][lr][lg * 8]);
        bfx8 ap1 = *reinterpret_cast<const bfx8*>(&sP[wave][lr][32 + lg * 8]);
        #pragma unroll
        for (int d = 0; d < 4; ++d) {
            bfx8 bv0 = *reinterpret_cast<const bfx8*>(&sVt[d * 16 + lr][lg * 8]);
            bfx8 bv1 = *reinterpret_cast<const bfx8*>(&sVt[d * 16 + lr][32 + lg * 8]);
            acc_o[d] = __builtin_amdgcn_mfma_f32_16x16x32_bf16(ap0, bv0, acc_o[d], 0, 0, 0);
            acc_o[d] = __builtin_amdgcn_mfma_f32_16x16x32_bf16(ap1, bv1, acc_o[d], 0, 0, 0);
        }
    }

    const int qrb = q0 + wave * 16 + lg * 4;
    #pragma unroll
    for (int d = 0; d < 4; ++d) {
        int col = hcol + d * 16 + lr;
        #pragma unroll
        for (int r = 0; r < 4; ++r) {
            float val = acc_o[d][r] / l_run[r];
            C[(rowbase + qrb + r) * DMODEL + col] = f2bf(val);
        }
    }
}

// ---------------------------------------------------------------------------
extern "C" void kernel_launch(void* const* d_in, const int* in_sizes, int n_in,
                              void* d_out, int out_size, void* d_ws, size_t ws_size,
                              hipStream_t stream)
{
    const float* q  = (const float*)d_in[0];
    const float* k  = (const float*)d_in[1];
    const float* v  = (const float*)d_in[2];
    const float* Wq = (const float*)d_in[3];
    const float* bq = (const float*)d_in[4];
    const float* Wk = (const float*)d_in[5];
    const float* bk = (const float*)d_in[6];
    const float* Wv = (const float*)d_in[7];
    const float* bv = (const float*)d_in[8];
    const float* Wf = (const float*)d_in[9];
    const float* bf = (const float*)d_in[10];
    float* out = (float*)d_out;

    // ws layout (ushort elems): Qb[0,8M) Kb[8M,16M) Vb/Cb[16M,24M) Vt[24M,32M)
    unsigned short* ws = (unsigned short*)d_ws;
    const size_t SZ = (size_t)MROWS * DMODEL;        // 8388608
    unsigned short* Qb = ws;
    unsigned short* Kb = ws + SZ;
    unsigned short* Vb = ws + 2 * SZ;                // becomes Cb after transpose
    unsigned short* Vt = ws + 3 * SZ;
    unsigned short* Cb = Vb;

    // d_out (32MB fp32) doubles as scratch for transposed bf16 weights (6MB)
    unsigned short* scr = (unsigned short*)d_out;
    unsigned short* WqT = scr;
    unsigned short* WkT = scr + 1048576;
    unsigned short* WvT = scr + 2097152;
    unsigned short* WfT = Qb;                        // Qb is dead after attn

    dim3 tcv(16, 16);
    transpose_cvt_kernel<<<tcv, 256, 0, stream>>>(Wq, WqT, DMODEL, DMODEL);
    transpose_cvt_kernel<<<tcv, 256, 0, stream>>>(Wk, WkT, DMODEL, DMODEL);
    transpose_cvt_kernel<<<tcv, 256, 0, stream>>>(Wv, WvT, DMODEL, DMODEL);

    dim3 gblk(MROWS / 128, DMODEL / 128);            // 64 x 8
    gemm_kernel<false, true><<<gblk, 256, 0, stream>>>(q, WqT, bq, Qb, MROWS, DMODEL, DMODEL);
    gemm_kernel<false, true><<<gblk, 256, 0, stream>>>(k, WkT, bk, Kb, MROWS, DMODEL, DMODEL);
    gemm_kernel<false, true><<<gblk, 256, 0, stream>>>(v, WvT, bv, Vb, MROWS, DMODEL, DMODEL);

    transpose_v_kernel<<<dim3(SS / 64, BB * NHEAD), 256, 0, stream>>>(Vb, Vt);

    attn_kernel<<<dim3(BB * NHEAD, SS / 64), 256, 0, stream>>>(Qb, Kb, Vt, Cb);

    transpose_cvt_kernel<<<tcv, 256, 0, stream>>>(Wf, WfT, DMODEL, DMODEL);

    gemm_kernel<true, false><<<gblk, 256, 0, stream>>>(Cb, WfT, bf, out, MROWS, DMODEL, DMODEL);
}

// Round 3
// 252.912 us; speedup vs baseline: 3.2288x; 1.4052x over previous
//
#include <hip/hip_runtime.h>
#include <stdint.h>

#define DMODEL 1024
#define NHEAD 16
#define DH 64
#define BB 4
#define SS 2048
#define MROWS (BB * SS)   // 8192

typedef __bf16 bfx8 __attribute__((ext_vector_type(8)));
typedef float f32x4 __attribute__((ext_vector_type(4)));
typedef float fvec4 __attribute__((ext_vector_type(4)));
typedef unsigned short u16x8 __attribute__((ext_vector_type(8)));
typedef unsigned short u16x4 __attribute__((ext_vector_type(4)));

__device__ __forceinline__ unsigned short f2bf(float f) {
    union { float f; unsigned int u; } v; v.f = f;
    unsigned int r = v.u + 0x7FFFu + ((v.u >> 16) & 1u);
    return (unsigned short)(r >> 16);
}

// async global->LDS, 16B per lane. LDS dest must be linear: wave base + lane*16.
typedef __attribute__((address_space(1))) const void gas_t;
typedef __attribute__((address_space(3))) void las_t;
__device__ __forceinline__ void gload_lds16(const void* g, void* l) {
    __builtin_amdgcn_global_load_lds((gas_t*)g, (las_t*)l, 16, 0, 0);
}

// ---------------------------------------------------------------------------
// fp32 -> bf16 convert (vectorized, 8 elems/thread)
// ---------------------------------------------------------------------------
__global__ void cvt_bf16_kernel(const float* __restrict__ src,
                                unsigned short* __restrict__ dst, int n8)
{
    int i = blockIdx.x * blockDim.x + threadIdx.x;
    if (i >= n8) return;
    fvec4 a = *reinterpret_cast<const fvec4*>(&src[(size_t)i * 8]);
    fvec4 b = *reinterpret_cast<const fvec4*>(&src[(size_t)i * 8 + 4]);
    u16x8 o;
    #pragma unroll
    for (int j = 0; j < 4; ++j) { o[j] = f2bf(a[j]); o[j + 4] = f2bf(b[j]); }
    *reinterpret_cast<u16x8*>(&dst[(size_t)i * 8]) = o;
}

// ---------------------------------------------------------------------------
// Transpose + convert: Wt[n][k] (bf16) = W[k][n] (fp32).  64x64 tiles.
// ---------------------------------------------------------------------------
__global__ void transpose_cvt_kernel(const float* __restrict__ W,
                                     unsigned short* __restrict__ Wt,
                                     int rows, int cols)
{
    __shared__ unsigned short t[64][76];
    const int tid = threadIdx.x;
    const int r0 = blockIdx.y * 64, c0 = blockIdx.x * 64;
    #pragma unroll
    for (int i = 0; i < 4; ++i) {
        int idx = tid + i * 256;
        int r = idx >> 4, c4 = idx & 15;
        fvec4 v = *reinterpret_cast<const fvec4*>(&W[(size_t)(r0 + r) * cols + c0 + c4 * 4]);
        #pragma unroll
        for (int j = 0; j < 4; ++j) t[c4 * 4 + j][r] = f2bf(v[j]);
    }
    __syncthreads();
    #pragma unroll
    for (int i = 0; i < 2; ++i) {
        int idx = tid + i * 256;
        int r = idx >> 3, c8 = idx & 7;
        u16x8 v = *reinterpret_cast<const u16x8*>(&t[r][c8 * 8]);
        *reinterpret_cast<u16x8*>(&Wt[(size_t)(c0 + r) * rows + r0 + c8 * 8]) = v;
    }
}

// ---------------------------------------------------------------------------
// Per-head V transpose: Vt[bh][d][s] = Vb[b*S+s][h*64+d]  (bf16 -> bf16)
// ---------------------------------------------------------------------------
__global__ void transpose_v_kernel(const unsigned short* __restrict__ Vb,
                                   unsigned short* __restrict__ Vt)
{
    __shared__ unsigned short t[64][76];
    const int tid = threadIdx.x;
    const int s0 = blockIdx.x * 64, bh = blockIdx.y;
    const int b = bh >> 4, h = bh & 15;
    #pragma unroll
    for (int i = 0; i < 2; ++i) {
        int idx = tid + i * 256;
        int sr = idx >> 3, c8 = idx & 7;
        u16x8 v = *reinterpret_cast<const u16x8*>(
            &Vb[((size_t)b * SS + s0 + sr) * DMODEL + h * DH + c8 * 8]);
        #pragma unroll
        for (int j = 0; j < 8; ++j) t[c8 * 8 + j][sr] = v[j];
    }
    __syncthreads();
    #pragma unroll
    for (int i = 0; i < 2; ++i) {
        int idx = tid + i * 256;
        int dr = idx >> 3, s8 = idx & 7;
        u16x8 v = *reinterpret_cast<const u16x8*>(&t[dr][s8 * 8]);
        *reinterpret_cast<u16x8*>(&Vt[((size_t)bh * DH + dr) * SS + s0 + s8 * 8]) = v;
    }
}

// ---------------------------------------------------------------------------
// GEMM: out[M][N] = A[M][K] @ Bt[N][K]^T + bias[N], A/Bt bf16 via
// global_load_lds. Optional epilogue scale (for Q projection).
// 128x128 tile, BK=64, 256 thr = 4 waves, 32 MFMA/k-step.
// ---------------------------------------------------------------------------
template<bool OUT_BF16>
__global__ __launch_bounds__(256, 2)
void gemm_kernel(const unsigned short* __restrict__ A,
                 const unsigned short* __restrict__ Bt,
                 const float* __restrict__ bias, void* __restrict__ Ov,
                 int M, int N, int K, float oscale)
{
    __shared__ unsigned short sA[128 * 64];
    __shared__ unsigned short sB[128 * 64];
    const int tid  = threadIdx.x;
    const int lane = tid & 63;
    const int wave = tid >> 6;
    const int wm = (wave >> 1) * 64, wn = (wave & 1) * 64;
    const int m0 = blockIdx.x * 128, n0 = blockIdx.y * 128;
    const int lr = lane & 15;
    const int lg = lane >> 4;

    f32x4 acc[4][4] = {};

    for (int kk0 = 0; kk0 < K; kk0 += 64) {
        __syncthreads();
        #pragma unroll
        for (int i = 0; i < 4; ++i) {
            int c = tid + i * 256;
            int row = c >> 3, col8 = c & 7;
            gload_lds16(&A[(size_t)(m0 + row) * K + kk0 + col8 * 8], &sA[c * 8]);
        }
        #pragma unroll
        for (int i = 0; i < 4; ++i) {
            int c = tid + i * 256;
            int row = c >> 3, col8 = c & 7;
            gload_lds16(&Bt[(size_t)(n0 + row) * K + kk0 + col8 * 8], &sB[c * 8]);
        }
        __syncthreads();

        bfx8 af[4][2], bfr[4][2];
        #pragma unroll
        for (int m = 0; m < 4; ++m)
            #pragma unroll
            for (int kk = 0; kk < 2; ++kk)
                af[m][kk] = *reinterpret_cast<const bfx8*>(
                    &sA[(wm + m * 16 + lr) * 64 + kk * 32 + lg * 8]);
        #pragma unroll
        for (int n = 0; n < 4; ++n)
            #pragma unroll
            for (int kk = 0; kk < 2; ++kk)
                bfr[n][kk] = *reinterpret_cast<const bfx8*>(
                    &sB[(wn + n * 16 + lr) * 64 + kk * 32 + lg * 8]);
        #pragma unroll
        for (int kk = 0; kk < 2; ++kk)
            #pragma unroll
            for (int m = 0; m < 4; ++m)
                #pragma unroll
                for (int n = 0; n < 4; ++n)
                    acc[m][n] = __builtin_amdgcn_mfma_f32_16x16x32_bf16(
                        af[m][kk], bfr[n][kk], acc[m][n], 0, 0, 0);
    }

    #pragma unroll
    for (int n = 0; n < 4; ++n) {
        int col = n0 + wn + n * 16 + lr;
        float bv = bias[col];
        #pragma unroll
        for (int m = 0; m < 4; ++m) {
            int rowb = m0 + wm + m * 16 + lg * 4;
            #pragma unroll
            for (int r = 0; r < 4; ++r) {
                float val = (acc[m][n][r] + bv) * oscale;
                if (OUT_BF16)
                    ((unsigned short*)Ov)[(size_t)(rowb + r) * N + col] = f2bf(val);
                else
                    ((float*)Ov)[(size_t)(rowb + r) * N + col] = val;
            }
        }
    }
}

// ---------------------------------------------------------------------------
// Flash-style causal attention. Q pre-scaled by 1/sqrt(2048)*log2(e).
// Q,K: [B*S][H*DH] bf16; Vt: [B*H][DH][S] bf16.
// Grid: x = B*H (64), y = 16 q-tiles of 128 rows (heavy-first).
// 256 thr = 4 waves x 32 q-rows. Defer-max fast path (scores << 8).
// ---------------------------------------------------------------------------
__global__ __launch_bounds__(256, 2)
void attn_kernel(const unsigned short* __restrict__ Q,
                 const unsigned short* __restrict__ K,
                 const unsigned short* __restrict__ Vt,
                 unsigned short* __restrict__ C)
{
    __shared__ unsigned short sK[64][76];        // [k][d]
    __shared__ unsigned short sVt[64][76];       // [d][k]
    __shared__ unsigned short sP[4][32][76];     // per-wave P [q][k]

    const int tid  = threadIdx.x;
    const int lane = tid & 63;
    const int wave = tid >> 6;
    const int lr = lane & 15, lg = lane >> 4;
    const int bh = blockIdx.x;
    const int qt = (int)(gridDim.y - 1) - (int)blockIdx.y;   // heavy tiles first
    const int b = bh >> 4, h = bh & 15;
    const int q0 = qt * 128;
    const size_t rowbase = (size_t)b * SS;
    const int hcol = h * DH;

    // Q fragments: 2 m-frags x 2 k-chunks
    bfx8 aq[2][2];
    #pragma unroll
    for (int m = 0; m < 2; ++m) {
        int qr = q0 + wave * 32 + m * 16 + lr;
        const unsigned short* p = &Q[(rowbase + qr) * DMODEL + hcol + lg * 8];
        aq[m][0] = *reinterpret_cast<const bfx8*>(p);
        aq[m][1] = *reinterpret_cast<const bfx8*>(p + 32);
    }

    float m_run[2][4], l_run[2][4];
    f32x4 acc_o[2][4];
    #pragma unroll
    for (int m = 0; m < 2; ++m)
        #pragma unroll
        for (int r = 0; r < 4; ++r) {
            m_run[m][r] = 0.f; l_run[m][r] = 0.f;
            acc_o[m][r] = f32x4{0.f, 0.f, 0.f, 0.f};
        }
    bool mz = true;                               // all m_run still 0
    const int qmax_wave = q0 + wave * 32 + 31;
    const int ntiles = 2 * qt + 2;

    for (int t = 0; t < ntiles; ++t) {
        const int k0 = t * 64;
        __syncthreads();
        #pragma unroll
        for (int i = 0; i < 2; ++i) {
            int idx = tid + i * 256;
            int kr = idx >> 3, c8 = idx & 7;
            *reinterpret_cast<u16x8*>(&sK[kr][c8 * 8]) =
                *reinterpret_cast<const u16x8*>(
                    &K[(rowbase + k0 + kr) * DMODEL + hcol + c8 * 8]);
            *reinterpret_cast<u16x8*>(&sVt[kr][c8 * 8]) =
                *reinterpret_cast<const u16x8*>(
                    &Vt[((size_t)bh * DH + kr) * SS + k0 + c8 * 8]);
        }
        __syncthreads();
        if (k0 > qmax_wave) continue;             // fully masked for this wave

        // ---- S = Q @ K^T  (scores already in exp2 domain via Q pre-scale)
        f32x4 sc[2][4];
        #pragma unroll
        for (int nf = 0; nf < 4; ++nf) {
            bfx8 bk0 = *reinterpret_cast<const bfx8*>(&sK[nf * 16 + lr][lg * 8]);
            bfx8 bk1 = *reinterpret_cast<const bfx8*>(&sK[nf * 16 + lr][32 + lg * 8]);
            #pragma unroll
            for (int m = 0; m < 2; ++m) {
                f32x4 s = {0.f, 0.f, 0.f, 0.f};
                s = __builtin_amdgcn_mfma_f32_16x16x32_bf16(aq[m][0], bk0, s, 0, 0, 0);
                s = __builtin_amdgcn_mfma_f32_16x16x32_bf16(aq[m][1], bk1, s, 0, 0, 0);
                sc[m][nf] = s;
            }
        }
        // ---- causal mask (diagonal-overlapping tiles only)
        #pragma unroll
        for (int m = 0; m < 2; ++m) {
            int qgb = q0 + wave * 32 + m * 16 + lg * 4;
            if (k0 + 63 > qgb) {
                #pragma unroll
                for (int nf = 0; nf < 4; ++nf) {
                    int kg = k0 + nf * 16 + lr;
                    #pragma unroll
                    for (int r = 0; r < 4; ++r)
                        if (kg > qgb + r) sc[m][nf][r] = -3.0e38f;
                }
            }
        }
        // ---- softmax: defer-max fast path
        float pmax = -3.0e38f;
        #pragma unroll
        for (int m = 0; m < 2; ++m)
            #pragma unroll
            for (int nf = 0; nf < 4; ++nf) {
                float a = fmaxf(fmaxf(sc[m][nf][0], sc[m][nf][1]),
                                fmaxf(sc[m][nf][2], sc[m][nf][3]));
                pmax = fmaxf(pmax, a);
            }
        if (mz && __all(pmax <= 8.0f)) {
            // fast: m stays 0, no rescale, per-lane partial l
            #pragma unroll
            for (int m = 0; m < 2; ++m)
                #pragma unroll
                for (int nf = 0; nf < 4; ++nf)
                    #pragma unroll
                    for (int r = 0; r < 4; ++r) {
                        float p = __builtin_exp2f(sc[m][nf][r]);
                        sc[m][nf][r] = p;
                        l_run[m][r] += p;
                    }
        } else {
            mz = false;
            #pragma unroll
            for (int m = 0; m < 2; ++m)
                #pragma unroll
                for (int r = 0; r < 4; ++r) {
                    float mx = fmaxf(fmaxf(sc[m][0][r], sc[m][1][r]),
                                     fmaxf(sc[m][2][r], sc[m][3][r]));
                    #pragma unroll
                    for (int o = 1; o < 16; o <<= 1) mx = fmaxf(mx, __shfl_xor(mx, o, 64));
                    float mnew = fmaxf(m_run[m][r], mx);
                    float fs = __builtin_exp2f(m_run[m][r] - mnew);
                    m_run[m][r] = mnew;
                    float ps = 0.f;
                    #pragma unroll
                    for (int nf = 0; nf < 4; ++nf) {
                        float p = __builtin_exp2f(sc[m][nf][r] - mnew);
                        sc[m][nf][r] = p; ps += p;
                    }
                    l_run[m][r] = l_run[m][r] * fs + ps;
                    #pragma unroll
                    for (int d = 0; d < 4; ++d) acc_o[m][d][r] *= fs;
                }
        }
        // ---- P -> LDS (bf16), per-wave tile
        #pragma unroll
        for (int m = 0; m < 2; ++m)
            #pragma unroll
            for (int nf = 0; nf < 4; ++nf)
                #pragma unroll
                for (int r = 0; r < 4; ++r)
                    sP[wave][m * 16 + lg * 4 + r][nf * 16 + lr] = f2bf(sc[m][nf][r]);
        asm volatile("s_waitcnt lgkmcnt(0)" ::: "memory");
        // ---- accumulate P @ V
        #pragma unroll
        for (int m = 0; m < 2; ++m) {
            bfx8 ap0 = *reinterpret_cast<const bfx8*>(&sP[wave][m * 16 + lr][lg * 8]);
            bfx8 ap1 = *reinterpret_cast<const bfx8*>(&sP[wave][m * 16 + lr][32 + lg * 8]);
            #pragma unroll
            for (int d = 0; d < 4; ++d) {
                bfx8 bv0 = *reinterpret_cast<const bfx8*>(&sVt[d * 16 + lr][lg * 8]);
                bfx8 bv1 = *reinterpret_cast<const bfx8*>(&sVt[d * 16 + lr][32 + lg * 8]);
                acc_o[m][d] = __builtin_amdgcn_mfma_f32_16x16x32_bf16(ap0, bv0, acc_o[m][d], 0, 0, 0);
                acc_o[m][d] = __builtin_amdgcn_mfma_f32_16x16x32_bf16(ap1, bv1, acc_o[m][d], 0, 0, 0);
            }
        }
    }

    // ---- epilogue: reduce per-lane l partials across the 16 lr lanes
    #pragma unroll
    for (int m = 0; m < 2; ++m)
        #pragma unroll
        for (int r = 0; r < 4; ++r) {
            float l = l_run[m][r];
            #pragma unroll
            for (int o = 1; o < 16; o <<= 1) l += __shfl_xor(l, o, 64);
            l_run[m][r] = 1.0f / l;
        }
    #pragma unroll
    for (int m = 0; m < 2; ++m) {
        const int qrb = q0 + wave * 32 + m * 16 + lg * 4;
        #pragma unroll
        for (int d = 0; d < 4; ++d) {
            int col = hcol + d * 16 + lr;
            #pragma unroll
            for (int r = 0; r < 4; ++r) {
                float val = acc_o[m][d][r] * l_run[m][r];
                C[(rowbase + qrb + r) * DMODEL + col] = f2bf(val);
            }
        }
    }
}

// ---------------------------------------------------------------------------
extern "C" void kernel_launch(void* const* d_in, const int* in_sizes, int n_in,
                              void* d_out, int out_size, void* d_ws, size_t ws_size,
                              hipStream_t stream)
{
    const float* q  = (const float*)d_in[0];
    const float* k  = (const float*)d_in[1];
    const float* v  = (const float*)d_in[2];
    const float* Wq = (const float*)d_in[3];
    const float* bq = (const float*)d_in[4];
    const float* Wk = (const float*)d_in[5];
    const float* bk = (const float*)d_in[6];
    const float* Wv = (const float*)d_in[7];
    const float* bv = (const float*)d_in[8];
    const float* Wf = (const float*)d_in[9];
    const float* bf = (const float*)d_in[10];

    // ws (64MB as 4 x SZ ushort slots) + d_out (32MB) as phased scratch
    unsigned short* ws = (unsigned short*)d_ws;
    const size_t SZ = (size_t)MROWS * DMODEL;        // 8388608 elems
    unsigned short* ws0 = ws;                        // qb16 -> Vb -> WfT
    unsigned short* ws1 = ws + SZ;                   // kb16 -> Vt
    unsigned short* ws2 = ws + 2 * SZ;               // vb16 -> Cb
    unsigned short* ws3 = ws + 3 * SZ;               // Kb

    unsigned short* scr = (unsigned short*)d_out;    // 16M ushorts
    unsigned short* WqT = scr;                       // 1M
    unsigned short* WkT = scr + 1048576;             // 1M
    unsigned short* WvT = scr + 2097152;             // 1M
    unsigned short* Qb  = scr + 3145728;             // 8M (ends at 11.25M < 16M)

    const float qscale = 0.02209708691207961f * 1.44269504088896341f;

    // 1. convert activations fp32 -> bf16
    const int n8 = (int)(SZ / 8);
    cvt_bf16_kernel<<<(n8 + 255) / 256, 256, 0, stream>>>(q, ws0, n8);
    cvt_bf16_kernel<<<(n8 + 255) / 256, 256, 0, stream>>>(k, ws1, n8);
    cvt_bf16_kernel<<<(n8 + 255) / 256, 256, 0, stream>>>(v, ws2, n8);

    // 2. transpose weights
    dim3 tcv(16, 16);
    transpose_cvt_kernel<<<tcv, 256, 0, stream>>>(Wq, WqT, DMODEL, DMODEL);
    transpose_cvt_kernel<<<tcv, 256, 0, stream>>>(Wk, WkT, DMODEL, DMODEL);
    transpose_cvt_kernel<<<tcv, 256, 0, stream>>>(Wv, WvT, DMODEL, DMODEL);

    // 3. projections (Q scaled into exp2 domain)
    dim3 gblk(MROWS / 128, DMODEL / 128);            // 64 x 8
    gemm_kernel<true><<<gblk, 256, 0, stream>>>(ws0, WqT, bq, Qb,  MROWS, DMODEL, DMODEL, qscale);
    gemm_kernel<true><<<gblk, 256, 0, stream>>>(ws1, WkT, bk, ws3, MROWS, DMODEL, DMODEL, 1.0f);
    gemm_kernel<true><<<gblk, 256, 0, stream>>>(ws2, WvT, bv, ws0, MROWS, DMODEL, DMODEL, 1.0f); // Vb

    // 4. per-head V transpose: Vb(ws0) -> Vt(ws1)
    transpose_v_kernel<<<dim3(SS / 64, BB * NHEAD), 256, 0, stream>>>(ws0, ws1);

    // 5. Wf transpose into ws0 (Vb dead)
    transpose_cvt_kernel<<<tcv, 256, 0, stream>>>(Wf, ws0, DMODEL, DMODEL);

    // 6. attention: Q=Qb K=ws3 Vt=ws1 -> Cb=ws2 (vb16 dead)
    attn_kernel<<<dim3(BB * NHEAD, SS / 128), 256, 0, stream>>>(Qb, ws3, ws1, ws2);

    // 7. output projection: Cb @ WfT + bf -> d_out (scratch regions dead)
    gemm_kernel<false><<<gblk, 256, 0, stream>>>(ws2, ws0, bf, (float*)d_out,
                                                 MROWS, DMODEL, DMODEL, 1.0f);
}

// Round 4
// 214.900 us; speedup vs baseline: 3.7999x; 1.1769x over previous
//
#include <hip/hip_runtime.h>
#include <stdint.h>

#define DMODEL 1024
#define NHEAD 16
#define DH 64
#define BB 4
#define SS 2048
#define MROWS (BB * SS)   // 8192

typedef __bf16 bfx8 __attribute__((ext_vector_type(8)));
typedef float f32x4 __attribute__((ext_vector_type(4)));
typedef float fvec4 __attribute__((ext_vector_type(4)));
typedef int i32x4 __attribute__((ext_vector_type(4)));
typedef unsigned short u16x8 __attribute__((ext_vector_type(8)));
typedef unsigned short u16x4 __attribute__((ext_vector_type(4)));

__device__ __forceinline__ unsigned short f2bf(float f) {
    union { float f; unsigned int u; } v; v.f = f;
    unsigned int r = v.u + 0x7FFFu + ((v.u >> 16) & 1u);
    return (unsigned short)(r >> 16);
}

// packed fp32x2 -> bf16x2 (RNE), single HW instruction
__device__ __forceinline__ unsigned int cvtpk(float lo, float hi) {
    unsigned int r;
    asm("v_cvt_pk_bf16_f32 %0, %1, %2" : "=v"(r) : "v"(lo), "v"(hi));
    return r;
}

// async global->LDS, 16B per lane. LDS dest must be linear: wave base + lane*16.
typedef __attribute__((address_space(1))) const void gas_t;
typedef __attribute__((address_space(3))) void las_t;
__device__ __forceinline__ void gload_lds16(const void* g, void* l) {
    __builtin_amdgcn_global_load_lds((gas_t*)g, (las_t*)l, 16, 0, 0);
}

// K-row permutation for swapped-QK in-register P trick.
// i bits [nf1 nf0 lg1 lg0 r1 r0] -> sigma bits [nf1 lg1 lg0 nf0 r1 r0]
__device__ __forceinline__ int sigma_k(int i) {
    return (i & 0x20) | ((i & 0x0C) << 1) | ((i & 0x10) >> 2) | (i & 3);
}

// ---------------------------------------------------------------------------
// fp32 -> bf16 convert for q,k,v in one launch (blockIdx.y selects tensor)
// ---------------------------------------------------------------------------
__global__ void cvt3_kernel(const float* __restrict__ s0, const float* __restrict__ s1,
                            const float* __restrict__ s2,
                            unsigned short* __restrict__ d0, unsigned short* __restrict__ d1,
                            unsigned short* __restrict__ d2, int n8)
{
    const float* s = (blockIdx.y == 0) ? s0 : (blockIdx.y == 1) ? s1 : s2;
    unsigned short* d = (blockIdx.y == 0) ? d0 : (blockIdx.y == 1) ? d1 : d2;
    int i = blockIdx.x * blockDim.x + threadIdx.x;
    if (i >= n8) return;
    fvec4 a = *reinterpret_cast<const fvec4*>(&s[(size_t)i * 8]);
    fvec4 b = *reinterpret_cast<const fvec4*>(&s[(size_t)i * 8 + 4]);
    u16x8 o;
    #pragma unroll
    for (int j = 0; j < 4; ++j) { o[j] = f2bf(a[j]); o[j + 4] = f2bf(b[j]); }
    *reinterpret_cast<u16x8*>(&d[(size_t)i * 8]) = o;
}

// ---------------------------------------------------------------------------
// Transpose + convert: Wt[n][k] (bf16) = W[k][n] (fp32). 64x64 tiles.
// blockIdx.z selects which weight (for the 3-in-1 launch).
// ---------------------------------------------------------------------------
__global__ void transpose_cvt3_kernel(const float* __restrict__ W0, unsigned short* __restrict__ T0,
                                      const float* __restrict__ W1, unsigned short* __restrict__ T1,
                                      const float* __restrict__ W2, unsigned short* __restrict__ T2)
{
    const float* W = (blockIdx.z == 0) ? W0 : (blockIdx.z == 1) ? W1 : W2;
    unsigned short* Wt = (blockIdx.z == 0) ? T0 : (blockIdx.z == 1) ? T1 : T2;
    __shared__ unsigned short t[64][72];
    const int tid = threadIdx.x;
    const int r0 = blockIdx.y * 64, c0 = blockIdx.x * 64;
    #pragma unroll
    for (int i = 0; i < 4; ++i) {
        int idx = tid + i * 256;
        int r = idx >> 4, c4 = idx & 15;
        fvec4 v = *reinterpret_cast<const fvec4*>(&W[(size_t)(r0 + r) * DMODEL + c0 + c4 * 4]);
        #pragma unroll
        for (int j = 0; j < 4; ++j) t[c4 * 4 + j][r] = f2bf(v[j]);
    }
    __syncthreads();
    #pragma unroll
    for (int i = 0; i < 2; ++i) {
        int idx = tid + i * 256;
        int r = idx >> 3, c8 = idx & 7;
        u16x8 v = *reinterpret_cast<const u16x8*>(&t[r][c8 * 8]);
        *reinterpret_cast<u16x8*>(&Wt[(size_t)(c0 + r) * DMODEL + r0 + c8 * 8]) = v;
    }
}

// ---------------------------------------------------------------------------
// Per-head V transpose: Vt[bh][d][s] = Vb[b*S+s][h*64+d]  (bf16 -> bf16)
// ---------------------------------------------------------------------------
__global__ void transpose_v_kernel(const unsigned short* __restrict__ Vb,
                                   unsigned short* __restrict__ Vt)
{
    __shared__ unsigned short t[64][72];
    const int tid = threadIdx.x;
    const int s0 = blockIdx.x * 64, bh = blockIdx.y;
    const int b = bh >> 4, h = bh & 15;
    #pragma unroll
    for (int i = 0; i < 2; ++i) {
        int idx = tid + i * 256;
        int sr = idx >> 3, c8 = idx & 7;
        u16x8 v = *reinterpret_cast<const u16x8*>(
            &Vb[((size_t)b * SS + s0 + sr) * DMODEL + h * DH + c8 * 8]);
        #pragma unroll
        for (int j = 0; j < 8; ++j) t[c8 * 8 + j][sr] = v[j];
    }
    __syncthreads();
    #pragma unroll
    for (int i = 0; i < 2; ++i) {
        int idx = tid + i * 256;
        int dr = idx >> 3, s8 = idx & 7;
        u16x8 v = *reinterpret_cast<const u16x8*>(&t[dr][s8 * 8]);
        *reinterpret_cast<u16x8*>(&Vt[((size_t)bh * DH + dr) * SS + s0 + s8 * 8]) = v;
    }
}

// ---------------------------------------------------------------------------
// GEMM: out[M][N] = A[M][K] @ Bt[N][K]^T + bias[N]; bf16 in via global_load_lds.
// 128x128 tile, BK=64, 256 thr = 4 waves, 32 MFMA/k-step. blockIdx.z picks arg set.
// ---------------------------------------------------------------------------
struct GArg {
    const unsigned short* A;
    const unsigned short* Bt;
    const float* bias;
    void* O;
    float osc;
};

template<bool OUT_BF16>
__global__ __launch_bounds__(256, 2)
void gemm_kernel(GArg g0, GArg g1, int M, int N, int K)
{
    const GArg g = blockIdx.z ? g1 : g0;
    __shared__ unsigned short sA[128 * 64];
    __shared__ unsigned short sB[128 * 64];
    const int tid  = threadIdx.x;
    const int lane = tid & 63;
    const int wave = tid >> 6;
    const int wm = (wave >> 1) * 64, wn = (wave & 1) * 64;
    const int m0 = blockIdx.x * 128, n0 = blockIdx.y * 128;
    const int lr = lane & 15;
    const int lg = lane >> 4;

    f32x4 acc[4][4] = {};

    for (int kk0 = 0; kk0 < K; kk0 += 64) {
        __syncthreads();
        #pragma unroll
        for (int i = 0; i < 4; ++i) {
            int c = tid + i * 256;
            int row = c >> 3, col8 = c & 7;
            gload_lds16(&g.A[(size_t)(m0 + row) * K + kk0 + col8 * 8], &sA[c * 8]);
        }
        #pragma unroll
        for (int i = 0; i < 4; ++i) {
            int c = tid + i * 256;
            int row = c >> 3, col8 = c & 7;
            gload_lds16(&g.Bt[(size_t)(n0 + row) * K + kk0 + col8 * 8], &sB[c * 8]);
        }
        __syncthreads();

        bfx8 af[4][2], bfr[4][2];
        #pragma unroll
        for (int m = 0; m < 4; ++m)
            #pragma unroll
            for (int kk = 0; kk < 2; ++kk)
                af[m][kk] = *reinterpret_cast<const bfx8*>(
                    &sA[(wm + m * 16 + lr) * 64 + kk * 32 + lg * 8]);
        #pragma unroll
        for (int n = 0; n < 4; ++n)
            #pragma unroll
            for (int kk = 0; kk < 2; ++kk)
                bfr[n][kk] = *reinterpret_cast<const bfx8*>(
                    &sB[(wn + n * 16 + lr) * 64 + kk * 32 + lg * 8]);
        #pragma unroll
        for (int kk = 0; kk < 2; ++kk)
            #pragma unroll
            for (int m = 0; m < 4; ++m)
                #pragma unroll
                for (int n = 0; n < 4; ++n)
                    acc[m][n] = __builtin_amdgcn_mfma_f32_16x16x32_bf16(
                        af[m][kk], bfr[n][kk], acc[m][n], 0, 0, 0);
    }

    #pragma unroll
    for (int n = 0; n < 4; ++n) {
        int col = n0 + wn + n * 16 + lr;
        float bv = g.bias[col];
        #pragma unroll
        for (int m = 0; m < 4; ++m) {
            int rowb = m0 + wm + m * 16 + lg * 4;
            #pragma unroll
            for (int r = 0; r < 4; ++r) {
                float val = (acc[m][n][r] + bv) * g.osc;
                if (OUT_BF16)
                    ((unsigned short*)g.O)[(size_t)(rowb + r) * N + col] = f2bf(val);
                else
                    ((float*)g.O)[(size_t)(rowb + r) * N + col] = val;
            }
        }
    }
}

// ---------------------------------------------------------------------------
// Flash-style causal attention, swapped-QK^T with sigma-permuted K rows.
// Q pre-scaled by 1/sqrt(2048)*log2(e). Q,K: [B*S][H*DH] bf16; Vt: [B*H][DH][S].
// Grid: x = B*H (64), y = 16 q-tiles of 128 (heavy-first). 4 waves x 32 q-rows.
// P stays in registers: lane owns q=lane&15; sigma-permutation makes the 16
// in-lane score values land exactly at the PV A-fragment slots.
// ---------------------------------------------------------------------------
__global__ __launch_bounds__(256, 2)
void attn_kernel(const unsigned short* __restrict__ Q,
                 const unsigned short* __restrict__ K,
                 const unsigned short* __restrict__ Vt,
                 unsigned short* __restrict__ C)
{
    __shared__ unsigned short sK[64][72];        // row i = K row k0+sigma(i), [k][d]
    __shared__ unsigned short sVt[64][72];       // [d][k] natural k order

    const int tid  = threadIdx.x;
    const int lane = tid & 63;
    const int wave = tid >> 6;
    const int lr = lane & 15, lg = lane >> 4;
    const int bh = blockIdx.x;
    const int qt = (int)(gridDim.y - 1) - (int)blockIdx.y;   // heavy tiles first
    const int b = bh >> 4, h = bh & 15;
    const int q0 = qt * 128;
    const size_t rowbase = (size_t)b * SS;
    const int hcol = h * DH;

    // staging coords (constant per thread)
    const int srow = tid >> 3, sc8 = tid & 7;
    const int sig0 = sigma_k(srow), sig1 = sigma_k(srow + 32);

    // Q fragments: 2 m-frags x 2 d-chunks (B-operand of swapped mfma)
    bfx8 aq[2][2];
    #pragma unroll
    for (int m = 0; m < 2; ++m) {
        int qr = q0 + wave * 32 + m * 16 + lr;
        const unsigned short* p = &Q[(rowbase + qr) * DMODEL + hcol + lg * 8];
        aq[m][0] = *reinterpret_cast<const bfx8*>(p);
        aq[m][1] = *reinterpret_cast<const bfx8*>(p + 32);
    }

    float m_run[2] = {0.f, 0.f};          // per-lane (q = lr) running max, exp2 dom
    f32x4 l4[2] = {};                     // per-lane partial sum-of-P (vector)
    f32x4 acc_o[2][4] = {};
    bool mz = true;
    const int qmax_wave = q0 + wave * 32 + 31;
    const int ntiles = 2 * qt + 2;

    for (int t = 0; t < ntiles; ++t) {
        const int k0 = t * 64;
        __syncthreads();
        // ---- stage K (sigma-permuted rows) and Vt (natural)
        *reinterpret_cast<u16x8*>(&sK[srow][sc8 * 8]) =
            *reinterpret_cast<const u16x8*>(
                &K[(rowbase + k0 + sig0) * DMODEL + hcol + sc8 * 8]);
        *reinterpret_cast<u16x8*>(&sK[srow + 32][sc8 * 8]) =
            *reinterpret_cast<const u16x8*>(
                &K[(rowbase + k0 + sig1) * DMODEL + hcol + sc8 * 8]);
        *reinterpret_cast<u16x8*>(&sVt[srow][sc8 * 8]) =
            *reinterpret_cast<const u16x8*>(
                &Vt[((size_t)bh * DH + srow) * SS + k0 + sc8 * 8]);
        *reinterpret_cast<u16x8*>(&sVt[srow + 32][sc8 * 8]) =
            *reinterpret_cast<const u16x8*>(
                &Vt[((size_t)bh * DH + srow + 32) * SS + k0 + sc8 * 8]);
        __syncthreads();
        if (k0 > qmax_wave) continue;     // fully masked for this wave

        // ---- S^T = K_perm @ Q : sc[m][nf][r] = S[q=lr][k = k0+sig(nf*16+lg*4+r)]
        f32x4 sc[2][4];
        #pragma unroll
        for (int nf = 0; nf < 4; ++nf) {
            bfx8 ak0 = *reinterpret_cast<const bfx8*>(&sK[nf * 16 + lr][lg * 8]);
            bfx8 ak1 = *reinterpret_cast<const bfx8*>(&sK[nf * 16 + lr][32 + lg * 8]);
            #pragma unroll
            for (int m = 0; m < 2; ++m) {
                f32x4 s = {0.f, 0.f, 0.f, 0.f};
                s = __builtin_amdgcn_mfma_f32_16x16x32_bf16(ak0, aq[m][0], s, 0, 0, 0);
                s = __builtin_amdgcn_mfma_f32_16x16x32_bf16(ak1, aq[m][1], s, 0, 0, 0);
                sc[m][nf] = s;
            }
        }
        // ---- causal mask: k = kb + r, q = qrow
        #pragma unroll
        for (int m = 0; m < 2; ++m) {
            if (k0 + 63 > q0 + wave * 32 + m * 16) {
                int qrow = q0 + wave * 32 + m * 16 + lr;
                #pragma unroll
                for (int nf = 0; nf < 4; ++nf) {
                    int kb = k0 + ((nf >> 1) << 5) + (lg << 3) + ((nf & 1) << 2);
                    #pragma unroll
                    for (int r = 0; r < 4; ++r)
                        if (kb + r > qrow) sc[m][nf][r] = -3.0e38f;
                }
            }
        }
        // ---- softmax: defer-max fast path (exp2 domain, max stays 0)
        f32x4 mx4 = sc[0][0];
        #pragma unroll
        for (int m = 0; m < 2; ++m)
            #pragma unroll
            for (int nf = 0; nf < 4; ++nf)
                #pragma unroll
                for (int r = 0; r < 4; ++r) mx4[r] = fmaxf(mx4[r], sc[m][nf][r]);
        float pmax = fmaxf(fmaxf(mx4[0], mx4[1]), fmaxf(mx4[2], mx4[3]));
        if (mz && __all(pmax <= 8.0f)) {
            #pragma unroll
            for (int m = 0; m < 2; ++m)
                #pragma unroll
                for (int nf = 0; nf < 4; ++nf) {
                    #pragma unroll
                    for (int r = 0; r < 4; ++r)
                        sc[m][nf][r] = __builtin_exp2f(sc[m][nf][r]);
                    l4[m] += sc[m][nf];
                }
        } else {
            mz = false;
            #pragma unroll
            for (int m = 0; m < 2; ++m) {
                float mx = fmaxf(fmaxf(mx4[0], mx4[1]), fmaxf(mx4[2], mx4[3]));
                // recompute per-m in-lane max (mx4 covered both m)
                mx = -3.0e38f;
                #pragma unroll
                for (int nf = 0; nf < 4; ++nf)
                    #pragma unroll
                    for (int r = 0; r < 4; ++r) mx = fmaxf(mx, sc[m][nf][r]);
                mx = fmaxf(mx, __shfl_xor(mx, 16, 64));
                mx = fmaxf(mx, __shfl_xor(mx, 32, 64));
                float mnew = fmaxf(m_run[m], mx);
                float fs = __builtin_exp2f(m_run[m] - mnew);
                m_run[m] = mnew;
                f32x4 ps = {0.f, 0.f, 0.f, 0.f};
                #pragma unroll
                for (int nf = 0; nf < 4; ++nf) {
                    #pragma unroll
                    for (int r = 0; r < 4; ++r)
                        sc[m][nf][r] = __builtin_exp2f(sc[m][nf][r] - mnew);
                    ps += sc[m][nf];
                }
                #pragma unroll
                for (int r = 0; r < 4; ++r) l4[m][r] = l4[m][r] * fs + ps[r];
                #pragma unroll
                for (int r = 0; r < 4; ++r) {
                    float fsa = __shfl(fs, lg * 4 + r, 64);
                    #pragma unroll
                    for (int d = 0; d < 4; ++d) acc_o[m][d][r] *= fsa;
                }
            }
        }
        // ---- pack P (in-register!) and accumulate P @ V
        #pragma unroll
        for (int h2 = 0; h2 < 2; ++h2) {
            union { i32x4 i; bfx8 b; } pa[2];
            #pragma unroll
            for (int m = 0; m < 2; ++m) {
                pa[m].i[0] = cvtpk(sc[m][2 * h2][0],     sc[m][2 * h2][1]);
                pa[m].i[1] = cvtpk(sc[m][2 * h2][2],     sc[m][2 * h2][3]);
                pa[m].i[2] = cvtpk(sc[m][2 * h2 + 1][0], sc[m][2 * h2 + 1][1]);
                pa[m].i[3] = cvtpk(sc[m][2 * h2 + 1][2], sc[m][2 * h2 + 1][3]);
            }
            #pragma unroll
            for (int d = 0; d < 4; ++d) {
                bfx8 bv = *reinterpret_cast<const bfx8*>(&sVt[d * 16 + lr][h2 * 32 + lg * 8]);
                acc_o[0][d] = __builtin_amdgcn_mfma_f32_16x16x32_bf16(pa[0].b, bv, acc_o[0][d], 0, 0, 0);
                acc_o[1][d] = __builtin_amdgcn_mfma_f32_16x16x32_bf16(pa[1].b, bv, acc_o[1][d], 0, 0, 0);
            }
        }
    }

    // ---- epilogue: l = hsum(l4) reduced across lg group; broadcast to acc rows
    #pragma unroll
    for (int m = 0; m < 2; ++m) {
        float l = (l4[m][0] + l4[m][1]) + (l4[m][2] + l4[m][3]);
        l += __shfl_xor(l, 16, 64);
        l += __shfl_xor(l, 32, 64);
        float linv = 1.0f / l;                   // valid at q = lr
        float linva[4];
        #pragma unroll
        for (int r = 0; r < 4; ++r) linva[r] = __shfl(linv, lg * 4 + r, 64);
        const int qrb = q0 + wave * 32 + m * 16 + lg * 4;
        #pragma unroll
        for (int d = 0; d < 4; ++d) {
            int col = hcol + d * 16 + lr;
            #pragma unroll
            for (int r = 0; r < 4; ++r)
                C[(rowbase + qrb + r) * DMODEL + col] = f2bf(acc_o[m][d][r] * linva[r]);
        }
    }
}

// ---------------------------------------------------------------------------
extern "C" void kernel_launch(void* const* d_in, const int* in_sizes, int n_in,
                              void* d_out, int out_size, void* d_ws, size_t ws_size,
                              hipStream_t stream)
{
    const float* q  = (const float*)d_in[0];
    const float* k  = (const float*)d_in[1];
    const float* v  = (const float*)d_in[2];
    const float* Wq = (const float*)d_in[3];
    const float* bq = (const float*)d_in[4];
    const float* Wk = (const float*)d_in[5];
    const float* bk = (const float*)d_in[6];
    const float* Wv = (const float*)d_in[7];
    const float* bv = (const float*)d_in[8];
    const float* Wf = (const float*)d_in[9];
    const float* bf = (const float*)d_in[10];

    unsigned short* ws = (unsigned short*)d_ws;
    const size_t SZ = (size_t)MROWS * DMODEL;        // 8388608 elems
    unsigned short* ws0 = ws;                        // qb16 -> Vb -> WfT
    unsigned short* ws1 = ws + SZ;                   // kb16 -> Vt
    unsigned short* ws2 = ws + 2 * SZ;               // vb16 -> Cb
    unsigned short* ws3 = ws + 3 * SZ;               // Kb

    unsigned short* scr = (unsigned short*)d_out;    // 16M ushorts scratch
    unsigned short* WqT = scr;                       // [0,1M)
    unsigned short* WkT = scr + 1048576;             // [1M,2M)
    unsigned short* WvT = scr + 2097152;             // [2M,3M)
    unsigned short* Qb  = scr + 4194304;             // [4M,12M)

    const float qscale = 0.02209708691207961f * 1.44269504088896341f;

    // 1. q,k,v fp32 -> bf16 (one launch)
    const int n8 = (int)(SZ / 8);
    cvt3_kernel<<<dim3((n8 + 255) / 256, 3), 256, 0, stream>>>(q, k, v, ws0, ws1, ws2, n8);

    // 2. Wq/Wk/Wv transpose (one launch)
    transpose_cvt3_kernel<<<dim3(16, 16, 3), 256, 0, stream>>>(Wq, WqT, Wk, WkT, Wv, WvT);

    // 3. Q and K projections in one launch (z=2); Q scaled into exp2 domain
    dim3 gblk2(MROWS / 128, DMODEL / 128, 2);
    {
        GArg gq{ws0, WqT, bq, Qb,  qscale};
        GArg gk{ws1, WkT, bk, ws3, 1.0f};
        gemm_kernel<true><<<gblk2, 256, 0, stream>>>(gq, gk, MROWS, DMODEL, DMODEL);
    }
    // 4. V projection -> ws0 (qb16 dead)
    dim3 gblk1(MROWS / 128, DMODEL / 128, 1);
    {
        GArg gv{ws2, WvT, bv, ws0, 1.0f};
        gemm_kernel<true><<<gblk1, 256, 0, stream>>>(gv, gv, MROWS, DMODEL, DMODEL);
    }
    // 5. per-head V transpose: Vb(ws0) -> Vt(ws1)  (kb16 dead)
    transpose_v_kernel<<<dim3(SS / 64, BB * NHEAD), 256, 0, stream>>>(ws0, ws1);

    // 6. Wf transpose -> ws0 (Vb dead)
    transpose_cvt3_kernel<<<dim3(16, 16, 1), 256, 0, stream>>>(Wf, ws0, Wf, ws0, Wf, ws0);

    // 7. attention: Qb, Kb(ws3), Vt(ws1) -> Cb(ws2)  (vb16 dead)
    attn_kernel<<<dim3(BB * NHEAD, SS / 128), 256, 0, stream>>>(Qb, ws3, ws1, ws2);

    // 8. output projection: Cb @ WfT + bf -> d_out fp32
    {
        GArg gf{ws2, ws0, bf, (float*)d_out, 1.0f};
        gemm_kernel<false><<<gblk1, 256, 0, stream>>>(gf, gf, MROWS, DMODEL, DMODEL);
    }
}